// Round 4
// baseline (103.711 us; speedup 1.0000x reference)
//
#include <hip/hip_runtime.h>

// Hankel anti-diagonal segmented mean.
// Input:  delay_embedding [B=64, T=1024, E=2048] fp32
// Output: [B, E-1=2047] fp32; out[b,k] = mean over i of A[b, i, 1024+k-i],
//         i in [max(0, k-1023), 1023].
//
// For fixed row i, diagonal elements for consecutive k are contiguous:
// A[b,i,1024+k-i] = in[b*T*E + i*(E-1) + (T+k)].  Lanes map to k -> fully
// coalesced 1 KB wave segments; every input element read exactly once
// (402 MB total -> HBM-bound, ~64-68 us floor incl. line splits).
//
// Load balance by construction: one wave per block; each wave owns
// (b, k-group G of 256 k's, 64-row chunk rc), and ONLY valid (G,rc) pairs
// are dispatched: full region G<4 -> all 16 chunks; taper group g'=G-4 ->
// chunks rc >= 4g' (16+12+8+4 = 40). 104 uniform wave-units per batch,
// 6656 total; ~96% do exactly 64 float4-iters.
// Threads pre-scale partials by 1/cnt(k); atomicAdd into memset-zeroed out.

#define T_LEN 1024
#define E_LEN 2048
#define K_OUT (E_LEN - 1)   // 2047
#define B_SZ  64
#define RCH   64            // rows per chunk
#define UPB   104           // wave-units per batch: 64 full + 40 taper
#define NBLK  (UPB * B_SZ)  // 6656 blocks, 64 threads each

__global__ void __launch_bounds__(64)
diag_accum(const float* __restrict__ in, float* __restrict__ out) {
    const int b = blockIdx.x & (B_SZ - 1);
    const int u = blockIdx.x >> 6;          // 0..103 (full units first)

    int G, rc;
    if (u < 64) {            // full region: k < 1024
        G = u >> 4;          // 0..3
        rc = u & 15;
    } else {                 // taper: G = 4 + g', valid rc >= 4*g'
        const int t = u - 64;
        if (t < 16)      { G = 4; rc = t;      }
        else if (t < 28) { G = 5; rc = t - 12; }
        else if (t < 36) { G = 6; rc = t - 20; }
        else             { G = 7; rc = t - 24; }
    }

    const int k0 = G * 256 + (threadIdx.x << 2);  // 4 consecutive k's
    const int r0 = rc * RCH;
    const int r1 = r0 + RCH;

    const int il0 = max(r0, k0     - (T_LEN - 1));
    const int il3 = max(r0, k0 + 3 - (T_LEN - 1));
    if (il0 >= r1) return;

    const float* p = in + (size_t)b * T_LEN * E_LEN
                        + (size_t)il0 * (E_LEN - 1)
                        + (size_t)(T_LEN + k0);
    float sx = 0.f, sy = 0.f, sz = 0.f, sw = 0.f;
    int i = il0;

    // Ragged diagonal head (<=3 iters normally; whole chunk only for the
    // k0=2044 corner where comp3 would run off the buffer): scalar loads.
    const int head_end = min(il3, r1);
    for (; i < head_end; ++i) {
        sx += p[0];
        if (i >= k0 + 1 - (T_LEN - 1)) sy += p[1];
        if (i >= k0 + 2 - (T_LEN - 1)) sz += p[2];
        p += (E_LEN - 1);
    }

    // Main loop: all 4 components valid and in-bounds.
    #pragma unroll 8
    for (; i < r1; ++i) {
        float v[4];
        __builtin_memcpy(v, p, 16);   // unaligned-safe 16B load -> dwordx4
        sx += v[0]; sy += v[1]; sz += v[2]; sw += v[3];
        p += (E_LEN - 1);
    }

    // Pre-scale by 1/cnt(k) so atomics accumulate the final mean directly.
    const int ov = k0 - (T_LEN - 1);
    const float n0 = (float)(T_LEN - max(0, ov));
    const float n1 = (float)(T_LEN - max(0, ov + 1));
    const float n2 = (float)(T_LEN - max(0, ov + 2));
    float* o = out + (size_t)b * K_OUT + k0;
    atomicAdd(o + 0, sx * (1.0f / n0));
    atomicAdd(o + 1, sy * (1.0f / n1));
    atomicAdd(o + 2, sz * (1.0f / n2));
    if (k0 + 3 < K_OUT) {
        const float n3 = (float)(T_LEN - max(0, ov + 3));
        atomicAdd(o + 3, sw * (1.0f / n3));
    }
}

extern "C" void kernel_launch(void* const* d_in, const int* in_sizes, int n_in,
                              void* d_out, int out_size, void* d_ws, size_t ws_size,
                              hipStream_t stream) {
    const float* in = (const float*)d_in[0];
    float* out = (float*)d_out;

    // Zero the accumulator (d_out is poisoned once, never re-poisoned).
    hipMemsetAsync(out, 0, sizeof(float) * B_SZ * K_OUT, stream);

    diag_accum<<<NBLK, 64, 0, stream>>>(in, out);
}

// Round 5
// 86.026 us; speedup vs baseline: 1.2056x; 1.2056x over previous
//
#include <hip/hip_runtime.h>

// Hankel anti-diagonal segmented mean.
// Input:  delay_embedding [B=64, T=1024, E=2048] fp32
// Output: [B, E-1=2047] fp32; out[b,k] = mean over i of A[b, i, 1024+k-i],
//         i in [max(0, k-1023), 1023].
//
// For fixed row i, diagonal elements for consecutive k are contiguous:
// A[b,i,1024+k-i] = in[b*T*E + i*(E-1) + (T+k)] -> coalesced float4 reads,
// every input element read exactly once (402 MB -> HBM-bound, ~64 us floor).
//
// Decomposition: unit = (b, 512-k group G, 64-row chunk rc, k-half p).
// Block = 4 waves, same (b,G): wave w -> chunk rc = rcb+(w>>1), half p = w&1.
// Only valid (G,rc) pairs are enumerated: G=0,1 full (8 blocks each),
// G=2 all rc (8), G=3 rc>=8 (4) -> 28 blocks/batch, 1792 total: ALL blocks
// co-resident (<=2048 slots), 7 waves/SIMD, near-uniform weight.
// Waves write partial sums to private LDS regions (plain stores, no atomics,
// no init); one barrier; 512 combined values -> global HW f32 atomics
// (unsafeAtomicAdd = global_atomic_add_f32, no CAS loop).

#define T_LEN 1024
#define E_LEN 2048
#define K_OUT (E_LEN - 1)   // 2047
#define B_SZ  64
#define NBLK  (28 * B_SZ)   // 1792

__global__ void __launch_bounds__(256)
diag_accum(const float* __restrict__ in, float* __restrict__ out) {
    __shared__ float lacc[1024];   // 4 KB: [wave][256 k-slots]

    const int b  = blockIdx.x & (B_SZ - 1);
    const int u2 = blockIdx.x >> 6;          // 0..27

    int G, rcb;
    if (u2 < 8)       { G = 0; rcb = u2 * 2;            }
    else if (u2 < 16) { G = 1; rcb = (u2 - 8) * 2;      }
    else if (u2 < 24) { G = 2; rcb = (u2 - 16) * 2;     }
    else              { G = 3; rcb = 8 + (u2 - 24) * 2; }

    const int w    = threadIdx.x >> 6;       // wave 0..3
    const int lane = threadIdx.x & 63;
    const int rc   = rcb + (w >> 1);         // chunk for this wave
    const int p    = w & 1;                  // k-half

    const int k0 = G * 512 + p * 256 + (lane << 2);   // 4 consecutive k's
    const int r0 = rc * 64;
    const int r1 = r0 + 64;

    int il0       = max(r0, k0     - (T_LEN - 1));
    const int il3 = max(r0, k0 + 3 - (T_LEN - 1));

    float sx = 0.f, sy = 0.f, sz = 0.f, sw = 0.f;
    if (il0 < r1) {
        const float* pp = in + (size_t)b * T_LEN * E_LEN
                             + (size_t)il0 * (E_LEN - 1)
                             + (size_t)(T_LEN + k0);
        int i = il0;

        // Ragged diagonal head (<=3 iters; whole chunk only at the k0=2044
        // corner, which also keeps comp3 from reading past the buffer).
        const int head_end = min(il3, r1);
        for (; i < head_end; ++i) {
            sx += pp[0];
            if (i >= k0 + 1 - (T_LEN - 1)) sy += pp[1];
            if (i >= k0 + 2 - (T_LEN - 1)) sz += pp[2];
            pp += (E_LEN - 1);
        }

        // Main loop: all 4 components valid and in-bounds.
        #pragma unroll 8
        for (; i < r1; ++i) {
            float v[4];
            __builtin_memcpy(v, pp, 16);   // unaligned-safe -> dwordx4
            sx += v[0]; sy += v[1]; sz += v[2]; sw += v[3];
            pp += (E_LEN - 1);
        }
    }

    // Private region per wave: no races, no init needed (zero-trip lanes
    // store zeros). Region w holds k-local (w&1)*256 + [0,256).
    float4* dst = (float4*)&lacc[w * 256 + (lane << 2)];
    *dst = make_float4(sx, sy, sz, sw);
    __syncthreads();

    // Combine wave pairs {0,2} and {1,3}, scale by 1/cnt(k), HW f32 atomic.
    #pragma unroll 2
    for (int t = threadIdx.x; t < 512; t += 256) {
        const int k = G * 512 + t;
        if (k < K_OUT) {
            const float v = lacc[t] + lacc[512 + t];
            const int cnt = T_LEN - max(0, k - (T_LEN - 1));
            unsafeAtomicAdd(&out[(size_t)b * K_OUT + k], v * (1.0f / (float)cnt));
        }
    }
}

extern "C" void kernel_launch(void* const* d_in, const int* in_sizes, int n_in,
                              void* d_out, int out_size, void* d_ws, size_t ws_size,
                              hipStream_t stream) {
    const float* in = (const float*)d_in[0];
    float* out = (float*)d_out;

    // Zero the accumulator (d_out is poisoned once, never re-poisoned).
    hipMemsetAsync(out, 0, sizeof(float) * B_SZ * K_OUT, stream);

    diag_accum<<<NBLK, 256, 0, stream>>>(in, out);
}